// Round 13
// baseline (1353.622 us; speedup 1.0000x reference)
//
#include <hip/hip_runtime.h>

typedef unsigned short u16;
typedef unsigned int u32;
typedef unsigned long long u64;
typedef __attribute__((ext_vector_type(8))) short short8;
typedef __attribute__((ext_vector_type(4))) float f32x4;
typedef __attribute__((ext_vector_type(4))) u32 u32x4;
typedef __attribute__((ext_vector_type(2))) u32 u32x2;

#define RN_ 8388608  // B*T*H
#define MFMA16(a, b, c) __builtin_amdgcn_mfma_f32_16x16x32_bf16(a, b, c, 0, 0, 0)

__device__ __forceinline__ u16 f2bf(float f) {
  union { float f; u32 u; } v; v.f = f;
  u32 r = v.u + 0x7fffu + ((v.u >> 16) & 1u);  // RNE (inputs finite)
  return (u16)(r >> 16);
}
__device__ __forceinline__ float bf2f(u16 h) {
  union { u32 u; float f; } v; v.u = ((u32)h) << 16;
  return v.f;
}
__device__ __forceinline__ u32 pk2(float a, float b) {
  return (u32)f2bf(a) | ((u32)f2bf(b) << 16);
}
// scan column ordering (absolute R in [0,4096)):
// R = (k>>3 block of 8 units)*32 + (u&7)*4 + gate  ->  original g = gate*1024 + unit
__device__ __forceinline__ int permcol(int R) {
  return (R & 3) * 1024 + ((R >> 5) << 3) + ((R >> 2) & 7);
}
__device__ __forceinline__ float sigm(float x) { return 1.f / (1.f + __expf(-x)); }
__device__ __forceinline__ float tanh_(float x) {
  float e = __expf(2.f * x);
  return 1.f - 2.f / (e + 1.f);
}

// -------- transpose + convert + permute: four [4096][1024] bf16 buffers --------
__global__ __launch_bounds__(256) void transpose_convert(
    const float* __restrict__ Wx, const float* __restrict__ Wh,
    u16* __restrict__ WxT1, u16* __restrict__ WxT2,
    u16* __restrict__ WhT1, u16* __restrict__ WhT2) {
  __shared__ float lds[64][65];
  const int bid = blockIdx.x, tid = threadIdx.x;
  const int sel = bid >> 10;
  const int tile = bid & 1023;
  const int kt = tile & 15, rt = tile >> 4;  // 16 k-tiles x 64 R-tiles
  const float* src;
  u16* dst;
  if (sel == 0)      { src = Wx;                       dst = WxT1; }
  else if (sel == 1) { src = Wx + (size_t)1024 * 4096; dst = WxT2; }
  else if (sel == 2) { src = Wh;                       dst = WhT1; }
  else               { src = Wh + (size_t)1024 * 4096; dst = WhT2; }
#pragma unroll
  for (int ii = 0; ii < 16; ++ii) {
    int idx = ii * 256 + tid;
    int r = idx >> 6, c = idx & 63;
    int run = c >> 3, u = c & 7;
    int blkLoc = run >> 2, gate = run & 3;
    int g = gate * 1024 + (rt * 2 + blkLoc) * 8 + u;
    lds[r][blkLoc * 32 + u * 4 + gate] = src[(size_t)(kt * 64 + r) * 4096 + g];
  }
  __syncthreads();
#pragma unroll
  for (int ii = 0; ii < 16; ++ii) {
    int idx = ii * 256 + tid;
    int rw = idx >> 6, cw = idx & 63;
    dst[(size_t)(rt * 64 + rw) * 1024 + kt * 64 + cw] = f2bf(lds[cw][rw]);
  }
}

// -------- chunked GEMM group (persistent): 64 blocks, 32 chunks of 256 rows,
// 1 tile (128x128) per block per chunk.
// IS2=0: A = x (f32, rows remapped b*256+t), out -> xp1ring; gate: xp1 ring reuse.
// IS2=1: A = h1 read DIRECTLY from full-depth hpub1 ring (uncached); gate: scan1
//        chunk published + xp2 ring reuse vs scan2.
// C rows t-major (r = t*32+b), cols permuted; bias added here. C stores uncached.
// flags: [0..63] scan1, [64..127] scan2 (flag value = steps fully published+acked).
template <int IS2>
__device__ void gemm_grp(char* smem, int gb,
    const float* __restrict__ Af32, const u16* __restrict__ Ahp,
    const u16* __restrict__ Bt, const float* __restrict__ bias,
    u16* __restrict__ Cring, const int* flags, int* gdone) {
  u16* As = (u16*)smem;
  u16* Bs = (u16*)(smem + 16384);
  const int tid = threadIdx.x;
  const int lane = tid & 63, w = tid >> 6;
  const int wm = w >> 1, wn = w & 1;
  const int l15 = lane & 15, lq = lane >> 4;
  const int srow = tid >> 2, qd = tid & 3;
  const int mg = gb >> 5, ng = gb & 31;
  const u32 rsw = (u32)((l15 & 7) << 4);

  for (int c = 0; c < 32; ++c) {
    // ---- gate (once per chunk) ----
    if (w == 0) {
      const int thrA = IS2 ? 8 * (c + 1) : 8 * c - 24;  // scan1 flags
      const int thrB = 8 * c - 24;                       // scan2 flags (xp2 reuse)
      while (1) {
        bool ok = true;
        if (lane < 16) {
          u32x4 fv;
          const u32x4* fp = (const u32x4*)flags + lane;
          asm volatile("global_load_dwordx4 %0, %1, off sc0 sc1"
                       : "=v"(fv) : "v"(fp) : "memory");
          asm volatile("s_waitcnt vmcnt(0)" ::: "memory");
          __builtin_amdgcn_sched_barrier(0);
          ok = (int)fv[0] >= thrA && (int)fv[1] >= thrA &&
               (int)fv[2] >= thrA && (int)fv[3] >= thrA;
        } else if (IS2 && lane < 32) {
          u32x4 fv;
          const u32x4* fp = (const u32x4*)(flags + 64) + (lane - 16);
          asm volatile("global_load_dwordx4 %0, %1, off sc0 sc1"
                       : "=v"(fv) : "v"(fp) : "memory");
          asm volatile("s_waitcnt vmcnt(0)" ::: "memory");
          __builtin_amdgcn_sched_barrier(0);
          ok = (int)fv[0] >= thrB && (int)fv[1] >= thrB &&
               (int)fv[2] >= thrB && (int)fv[3] >= thrB;
        }
        if (__all(ok)) break;
        __builtin_amdgcn_s_sleep(8);
      }
    }
    __syncthreads();

    f32x4 acc[4][4];
#pragma unroll
    for (int i = 0; i < 4; ++i)
#pragma unroll
      for (int j = 0; j < 4; ++j) acc[i][j] = (f32x4){0.f, 0.f, 0.f, 0.f};

    for (int kt = 0; kt < 16; ++kt) {
      u32x4 aw[2][2], bv[2][2];
#pragma unroll
      for (int rr = 0; rr < 2; ++rr) {
        int row = rr * 64 + srow;
        const u32x4* bp = (const u32x4*)(Bt + (size_t)(ng * 128 + row) * 1024 + kt * 64 + qd * 16);
        bv[rr][0] = bp[0]; bv[rr][1] = bp[1];
        int rg = 256 * c + mg * 128 + row;
        if (IS2) {
          // h1 from hpub1 ring: slot t=rg>>5, batch b=rg&31, k-pack p=kt*8+qd*2
          int tq = rg >> 5, b2 = rg & 31;
          int p = kt * 8 + qd * 2;
          const char* ap = (const char*)Ahp + (size_t)tq * 65536 +
                           (size_t)(p * 32 + b2) * 16;
          asm volatile("global_load_dwordx4 %0, %1, off sc0 sc1"
                       : "=v"(aw[rr][0]) : "v"(ap) : "memory");
          asm volatile("global_load_dwordx4 %0, %1, off sc0 sc1"
                       : "=v"(aw[rr][1]) : "v"(ap + 512) : "memory");
        } else {
          const f32x4* ap = (const f32x4*)(Af32 +
              ((size_t)(rg & 31) * 256 + (rg >> 5)) * 1024 + kt * 64 + qd * 16);
          f32x4 a0 = ap[0], a1 = ap[1], a2 = ap[2], a3 = ap[3];
          aw[rr][0][0] = pk2(a0[0], a0[1]); aw[rr][0][1] = pk2(a0[2], a0[3]);
          aw[rr][0][2] = pk2(a1[0], a1[1]); aw[rr][0][3] = pk2(a1[2], a1[3]);
          aw[rr][1][0] = pk2(a2[0], a2[1]); aw[rr][1][1] = pk2(a2[2], a2[3]);
          aw[rr][1][2] = pk2(a3[0], a3[1]); aw[rr][1][3] = pk2(a3[2], a3[3]);
        }
      }
      __syncthreads();  // previous MFMA reads done before overwrite
      if (IS2) {
        asm volatile("s_waitcnt vmcnt(0)" ::: "memory");  // asm loads landed
        __builtin_amdgcn_sched_barrier(0);
      }
#pragma unroll
      for (int rr = 0; rr < 2; ++rr) {
        int row = rr * 64 + srow;
        u32 sw = (u32)((row & 7) << 4);
        int base = row * 128 + qd * 32;
        *(u32x4*)((char*)As + ((base) ^ sw)) = aw[rr][0];
        *(u32x4*)((char*)As + ((base + 16) ^ sw)) = aw[rr][1];
        *(u32x4*)((char*)Bs + ((base) ^ sw)) = bv[rr][0];
        *(u32x4*)((char*)Bs + ((base + 16) ^ sw)) = bv[rr][1];
      }
      __syncthreads();
#pragma unroll
      for (int k2 = 0; k2 < 2; ++k2) {
        short8 af[4], bf[4];
#pragma unroll
        for (int f = 0; f < 4; ++f) {
          af[f] = *(const short8*)((const char*)As +
                   (((wm * 64 + f * 16 + l15) * 128 + k2 * 64 + lq * 16) ^ rsw));
          bf[f] = *(const short8*)((const char*)Bs +
                   (((wn * 64 + f * 16 + l15) * 128 + k2 * 64 + lq * 16) ^ rsw));
        }
#pragma unroll
        for (int fi = 0; fi < 4; ++fi)
#pragma unroll
          for (int fj = 0; fj < 4; ++fj)
            acc[fi][fj] = MFMA16(af[fi], bf[fj], acc[fi][fj]);
      }
    }
    // ---- epilogue: +bias, store bf16 to ring slot c&3 (uncached) ----
#pragma unroll
    for (int fj = 0; fj < 4; ++fj) {
      int gc = ng * 128 + wn * 64 + fj * 16 + l15;
      float bvv = bias[permcol(gc)];
#pragma unroll
      for (int fi = 0; fi < 4; ++fi) {
        int rr0 = (c & 3) * 256 + mg * 128 + wm * 64 + fi * 16 + lq * 4;
#pragma unroll
        for (int r = 0; r < 4; ++r) {
          u32 vv = (u32)f2bf(acc[fi][fj][r] + bvv);
          const u16* cp = Cring + (size_t)(rr0 + r) * 4096 + gc;
          asm volatile("global_store_short %0, %1, off sc0 sc1"
                       :: "v"(cp), "v"(vv) : "memory");
        }
      }
    }
    asm volatile("s_waitcnt vmcnt(0)" ::: "memory");  // own stores acked
    __syncthreads();                                   // all waves drained
    if (tid == 0)
      __hip_atomic_fetch_add(gdone + c, 1, __ATOMIC_RELAXED, __HIP_MEMORY_SCOPE_AGENT);
  }
}

// -------- scan group (persistent): 64 blocks, 16 units each, K=1024 --------
// hpub = FULL-DEPTH poisoned ring (256 slots x 64KB, memset 0xFF per launch).
// Single-set data-poll with per-frag incremental re-poll. PUBLISH IS PER-THREAD
// DIRECT (2x2B stores right after the gates, BEFORE B2) -> no LDS gather, no
// wave-0 relay, publish overlaps other waves' tails. A 16B granule therefore
// aggregates stores from multiple threads/waves, so the poison check is
// PER-U16 (published h is finite -> never 0xFFFF; masked rows publish 0x0000).
// Progress flags are set passively after B1 at chunk boundaries: every wave's
// poll vmcnt(0) at step t retires its own step-(t-1) stores before B1, so
// B1(t) implies all publishes <= t-1 are globally acked -> tid0 stores flag=t.
#define ISSUE_FRAG(B, i_) do { \
  const int g_ = (i_) >> 2, j_ = (i_) & 3; \
  if (j_ == 0) asm volatile("global_load_dwordx4 %0, %1, off sc0 sc1" \
                            : "=v"(B[i_]) : "v"(pa[g_]) : "memory"); \
  else if (j_ == 1) asm volatile("global_load_dwordx4 %0, %1, off offset:256 sc0 sc1" \
                                 : "=v"(B[i_]) : "v"(pa[g_]) : "memory"); \
  else if (j_ == 2) asm volatile("global_load_dwordx4 %0, %1, off offset:2048 sc0 sc1" \
                                 : "=v"(B[i_]) : "v"(pa[g_]) : "memory"); \
  else asm volatile("global_load_dwordx4 %0, %1, off offset:2304 sc0 sc1" \
                    : "=v"(B[i_]) : "v"(pa[g_]) : "memory"); \
} while (0)
#define DRAIN0() do { asm volatile("s_waitcnt vmcnt(0)" ::: "memory"); \
  __builtin_amdgcn_sched_barrier(0); } while (0)
// B[i] <-> ks = i>>1, bc = i&1
#define MFALL(B) do { _Pragma("unroll") for (int i_ = 0; i_ < 16; ++i_) { \
  const int ks_ = i_ >> 1, bc_ = i_ & 1; \
  acc[0][bc_] = MFMA16(afr[0][ks_], B[i_], acc[0][bc_]); \
  acc[1][bc_] = MFMA16(afr[1][ks_], B[i_], acc[1][bc_]); \
  acc[2][bc_] = MFMA16(afr[2][ks_], B[i_], acc[2][bc_]); \
  acc[3][bc_] = MFMA16(afr[3][ks_], B[i_], acc[3][bc_]); } } while (0)

template <int L>
__device__ void scan_grp(char* smem, int nb,
    const u16* __restrict__ xpring, const u16* __restrict__ Wt,
    const int* __restrict__ lengths, u64* hpub,
    int* flags_self, const int* gdone,
    float* __restrict__ outp, float* __restrict__ csf, float* __restrict__ hsf) {
  f32x4* partv = (f32x4*)smem;                   // 32KB
  float* out_stage = (float*)(smem + 32768);     // 2KB  [b][16u] (L=1)
  const int tid = threadIdx.x;
  const int lane = tid & 63, w = tid >> 6;
  const int l15 = lane & 15, q = lane >> 4;
  const int b = (w & 1) * 16 + l15;
  const int u0 = (w >> 1) * 4 + q;  // 0..7; second unit = u0+8
  const int len = lengths[b];

  // Wh A-fragments register-resident: 32 x short8 = 128 VGPR
  short8 afr[4][8];
#pragma unroll
  for (int tt = 0; tt < 4; ++tt)
#pragma unroll
    for (int ks = 0; ks < 8; ++ks)
      afr[tt][ks] = *(const short8*)(Wt + (size_t)(nb * 64 + tt * 16 + l15) * 1024 +
                                     w * 256 + ks * 32 + q * 8);

  f32x4 acc[4][2];
#pragma unroll
  for (int tt = 0; tt < 4; ++tt)
#pragma unroll
    for (int bc = 0; bc < 2; ++bc) acc[tt][bc] = (f32x4){0.f, 0.f, 0.f, 0.f};
  float c0 = 0.f, h0 = 0.f, c1 = 0.f, h1 = 0.f;

  // per-lane poll base (k-pack group stride 4096B; offsets 0/256/2048/2304)
  const int lane_base = (w * 32 + q) * 512 + l15 * 16;
  // per-thread publish base within a slot: pack nb*2 + (u>>3), pos u&7
  const int pub_base = nb * 1024 + b * 16 + u0 * 2;

  for (int t = 0; t < 256; ++t) {
    // ---- chunk boundary: xp-chunk gate (1 in 8 steps) ----
    if ((t & 7) == 0) {
      if (w == 0) {
        const int cidx = t >> 3;
        while (1) {
          bool ok = true;
          if (lane == 0) {
            u32 cd;
            asm volatile("global_load_dword %0, %1, off sc0 sc1"
                         : "=v"(cd) : "v"(gdone + cidx) : "memory");
            asm volatile("s_waitcnt vmcnt(0)" ::: "memory");
            __builtin_amdgcn_sched_barrier(0);
            ok = (int)cd >= 64;
          }
          if (__all(ok)) break;
          __builtin_amdgcn_s_sleep(2);
        }
      }
      __syncthreads();
    }

    // ---- xp loads (uncached; ring slot (t>>3)&3, row (t&7)*32+b), 2 units ----
    const u16* xa = xpring + ((size_t)((t >> 3) & 3) * 256 + (t & 7) * 32 + b) * 4096 +
                    nb * 64 + u0 * 4;
    u32x2 xpv0, xpv1;
    asm volatile("global_load_dwordx2 %0, %1, off sc0 sc1"
                 : "=v"(xpv0) : "v"(xa) : "memory");
    asm volatile("global_load_dwordx2 %0, %1, off sc0 sc1"
                 : "=v"(xpv1) : "v"(xa + 32) : "memory");

    // ---- h fragments: single-set poll, per-frag re-poll, PER-U16 check ----
    if (t > 0) {
      const char* hp = (const char*)hpub + (size_t)(t - 1) * 65536 + lane_base;
      const char* pa[4];
#pragma unroll
      for (int g = 0; g < 4; ++g) pa[g] = hp + g * 4096;
      short8 bfv[16];
#pragma unroll
      for (int i = 0; i < 16; ++i) ISSUE_FRAG(bfv, i);
      u32 done = 0;
      while (1) {
        DRAIN0();  // all issued loads landed (also retires own stores of t-1)
        {
#pragma unroll
          for (int i = 0; i < 16; ++i) {
            if (!(done & (1u << i))) {
              u32x4 vv = __builtin_bit_cast(u32x4, bfv[i]);
              bool ok = true;
#pragma unroll
              for (int k = 0; k < 4; ++k) {
                ok = ok && ((vv[k] & 0xFFFFu) != 0xFFFFu) &&
                     (vv[k] < 0xFFFF0000u);
              }
              if (__all(ok)) done |= (1u << i);
            }
          }
        }
        if (done == 0xFFFFu) break;
#pragma unroll
        for (int i = 0; i < 16; ++i)
          if (!(done & (1u << i))) ISSUE_FRAG(bfv, i);
      }
      __builtin_amdgcn_sched_barrier(0);
      MFALL(bfv);
    } else {
      DRAIN0();
    }

    // ---- cross-wave K reduction (8 combos, 32 slots) ----
#pragma unroll
    for (int tt = 0; tt < 4; ++tt)
#pragma unroll
      for (int bc = 0; bc < 2; ++bc) {
        partv[(w * 8 + tt * 2 + bc) * 64 + lane] = acc[tt][bc];
        acc[tt][bc] = (f32x4){0.f, 0.f, 0.f, 0.f};
      }
    __syncthreads();  // B1: also implies all publishes <= t-1 globally acked
    if ((t & 7) == 0 && t > 0 && tid == 0)
      __hip_atomic_store(flags_self + nb, t, __ATOMIC_RELAXED,
                         __HIP_MEMORY_SCOPE_AGENT);
    f32x4 s0 = (f32x4){0.f, 0.f, 0.f, 0.f};
    f32x4 s1 = (f32x4){0.f, 0.f, 0.f, 0.f};
#pragma unroll
    for (int w2 = 0; w2 < 4; ++w2) {
      s0 += partv[(w2 * 8 + w) * 64 + lane];       // combo w   -> unit u0
      s1 += partv[(w2 * 8 + 4 + w) * 64 + lane];   // combo w+4 -> unit u0+8
    }

    bool mk = t < len;
    char* hb = (char*)hpub + (size_t)t * 65536 + pub_base;
    {
      float zi = s0[0] + bf2f((u16)(xpv0[0] & 0xffffu));
      float zj = s0[1] + bf2f((u16)(xpv0[0] >> 16));
      float zf = s0[2] + bf2f((u16)(xpv0[1] & 0xffffu)) + 1.f;  // FORGET_BIAS
      float zo = s0[3] + bf2f((u16)(xpv0[1] >> 16));
      float cn = sigm(zf) * c0 + sigm(zi) * tanh_(zj);
      float hn = sigm(zo) * tanh_(cn);
      c0 = mk ? cn : c0;
      h0 = mk ? hn : h0;
      float ov = mk ? hn : 0.f;
      u32 pv = (u32)f2bf(ov);
      asm volatile("global_store_short %0, %1, off sc0 sc1"
                   :: "v"(hb), "v"(pv) : "memory");  // unit u0, pack nb*2
      if (L) out_stage[b * 16 + u0] = ov;
    }
    {
      float zi = s1[0] + bf2f((u16)(xpv1[0] & 0xffffu));
      float zj = s1[1] + bf2f((u16)(xpv1[0] >> 16));
      float zf = s1[2] + bf2f((u16)(xpv1[1] & 0xffffu)) + 1.f;
      float zo = s1[3] + bf2f((u16)(xpv1[1] >> 16));
      float cn = sigm(zf) * c1 + sigm(zi) * tanh_(zj);
      float hn = sigm(zo) * tanh_(cn);
      c1 = mk ? cn : c1;
      h1 = mk ? hn : h1;
      float ov = mk ? hn : 0.f;
      u32 pv = (u32)f2bf(ov);
      asm volatile("global_store_short %0, %1, off sc0 sc1"
                   :: "v"(hb + 512), "v"(pv) : "memory");  // unit u0+8, pack nb*2+1
      if (L) out_stage[b * 16 + u0 + 8] = ov;
    }
    __syncthreads();  // B2: partv WAR + out_stage complete

    if (L && tid < 128) {  // rnnout rows (b, t), 16 cols
      int bb = tid >> 2, part = tid & 3;
      f32x4 ov = *(const f32x4*)(out_stage + bb * 16 + part * 4);
      *(f32x4*)(outp + ((size_t)bb * 256 + t) * 1024 + nb * 16 + part * 4) = ov;
    }
  }
  // final flag: all 256 steps published + acked
  DRAIN0();
  __syncthreads();
  if (tid == 0)
    __hip_atomic_store(flags_self + nb, 256, __ATOMIC_RELAXED,
                       __HIP_MEMORY_SCOPE_AGENT);
  csf[L * 32768 + b * 1024 + nb * 16 + u0] = c0;
  csf[L * 32768 + b * 1024 + nb * 16 + u0 + 8] = c1;
  hsf[L * 32768 + b * 1024 + nb * 16 + u0] = h0;
  hsf[L * 32768 + b * 1024 + nb * 16 + u0 + 8] = h1;
}

// -------- persistent pipeline: G1 64 | scan1 64 | G2 64 | scan2 64, 1 block/CU --------
__global__ __launch_bounds__(256, 1) void lstm_pipe(
    const float* __restrict__ x, const int* __restrict__ lengths,
    const float* __restrict__ bias,
    const u16* __restrict__ WxT1, const u16* __restrict__ WxT2,
    const u16* __restrict__ WhT1, const u16* __restrict__ WhT2,
    u16* xp1ring, u16* xp2ring,
    u64* hpub1, u64* hpub2, int* flags, float* outp) {
  __shared__ __align__(16) char smem[35840];
  int* g1done = flags + 128;   // 32 ints
  int* g2done = flags + 160;   // 32 ints
  const int bid = blockIdx.x;
  float* csf = outp + RN_;
  float* hsf = csf + 65536;
  if (bid < 64)
    gemm_grp<0>(smem, bid, x, nullptr, WxT1, bias, xp1ring, flags, g1done);
  else if (bid < 128)
    scan_grp<0>(smem, bid - 64, xp1ring, WhT1, lengths, hpub1, flags, g1done,
                outp, csf, hsf);
  else if (bid < 192)
    gemm_grp<1>(smem, bid - 128, nullptr, (const u16*)hpub1, WxT2, bias + 4096,
                xp2ring, flags, g2done);
  else
    scan_grp<1>(smem, bid - 192, xp2ring, WhT2, lengths, hpub2, flags + 64, g2done,
                outp, csf, hsf);
}

// -------- workspace layout (96MB + flags; proven budget) --------
#define WS_WXT1 0u
#define WS_WXT2 (8u << 20)
#define WS_WHT1 (16u << 20)
#define WS_WHT2 (24u << 20)
#define WS_XP1 (32u << 20)    // 4 slots x 256 rows x 4096 x 2B = 8MB
#define WS_XP2 (48u << 20)    // 8MB
#define WS_HPUB1 (64u << 20)  // 256 slots x 64KB = 16MB (full depth, poisoned)
#define WS_HPUB2 (80u << 20)  // 16MB (poisoned)
#define WS_FLAGS (96u << 20)  // 128 scan flags + 2x32 chunk counters

extern "C" void kernel_launch(void* const* d_in, const int* in_sizes, int n_in,
                              void* d_out, int out_size, void* d_ws, size_t ws_size,
                              hipStream_t stream) {
  const float* x = (const float*)d_in[0];
  const int* lengths = (const int*)d_in[1];
  const float* Wx = (const float*)d_in[2];
  const float* Wh = (const float*)d_in[3];
  const float* bias = (const float*)d_in[4];
  float* outp = (float*)d_out;

  if (ws_size < (size_t)WS_FLAGS + 4096) return;  // fail loudly (output stays poison)

  char* ws = (char*)d_ws;
  u16* WxT1 = (u16*)(ws + WS_WXT1);
  u16* WxT2 = (u16*)(ws + WS_WXT2);
  u16* WhT1 = (u16*)(ws + WS_WHT1);
  u16* WhT2 = (u16*)(ws + WS_WHT2);
  u16* xp1ring = (u16*)(ws + WS_XP1);
  u16* xp2ring = (u16*)(ws + WS_XP2);
  u64* hpub1 = (u64*)(ws + WS_HPUB1);
  u64* hpub2 = (u64*)(ws + WS_HPUB2);
  int* flags = (int*)(ws + WS_FLAGS);

  hipMemsetAsync(flags, 0, 2048, stream);
  hipMemsetAsync(hpub1, 0xFF, 32u << 20, stream);  // poison both hpub rings (NaN)
  transpose_convert<<<4096, 256, 0, stream>>>(Wx, Wh, WxT1, WxT2, WhT1, WhT2);
  lstm_pipe<<<256, 256, 0, stream>>>(x, lengths, bias, WxT1, WxT2, WhT1, WhT2,
                                     xp1ring, xp2ring, hpub1, hpub2, flags, outp);
}

// Round 14
// 1084.487 us; speedup vs baseline: 1.2482x; 1.2482x over previous
//
#include <hip/hip_runtime.h>

typedef unsigned short u16;
typedef unsigned int u32;
typedef unsigned long long u64;
typedef __attribute__((ext_vector_type(8))) short short8;
typedef __attribute__((ext_vector_type(4))) float f32x4;
typedef __attribute__((ext_vector_type(4))) u32 u32x4;
typedef __attribute__((ext_vector_type(2))) u32 u32x2;

#define RN_ 8388608  // B*T*H
#define MFMA16(a, b, c) __builtin_amdgcn_mfma_f32_16x16x32_bf16(a, b, c, 0, 0, 0)

__device__ __forceinline__ u16 f2bf(float f) {
  union { float f; u32 u; } v; v.f = f;
  u32 r = v.u + 0x7fffu + ((v.u >> 16) & 1u);  // RNE (inputs finite)
  return (u16)(r >> 16);
}
__device__ __forceinline__ float bf2f(u16 h) {
  union { u32 u; float f; } v; v.u = ((u32)h) << 16;
  return v.f;
}
__device__ __forceinline__ u32 pk2(float a, float b) {
  return (u32)f2bf(a) | ((u32)f2bf(b) << 16);
}
// scan column ordering (absolute R in [0,4096)):
// R = (k>>3 block of 8 units)*32 + (u&7)*4 + gate  ->  original g = gate*1024 + unit
__device__ __forceinline__ int permcol(int R) {
  return (R & 3) * 1024 + ((R >> 5) << 3) + ((R >> 2) & 7);
}
__device__ __forceinline__ float sigm(float x) { return 1.f / (1.f + __expf(-x)); }
__device__ __forceinline__ float tanh_(float x) {
  float e = __expf(2.f * x);
  return 1.f - 2.f / (e + 1.f);
}

// -------- transpose + convert + permute: four [4096][1024] bf16 buffers --------
__global__ __launch_bounds__(256) void transpose_convert(
    const float* __restrict__ Wx, const float* __restrict__ Wh,
    u16* __restrict__ WxT1, u16* __restrict__ WxT2,
    u16* __restrict__ WhT1, u16* __restrict__ WhT2) {
  __shared__ float lds[64][65];
  const int bid = blockIdx.x, tid = threadIdx.x;
  const int sel = bid >> 10;
  const int tile = bid & 1023;
  const int kt = tile & 15, rt = tile >> 4;  // 16 k-tiles x 64 R-tiles
  const float* src;
  u16* dst;
  if (sel == 0)      { src = Wx;                       dst = WxT1; }
  else if (sel == 1) { src = Wx + (size_t)1024 * 4096; dst = WxT2; }
  else if (sel == 2) { src = Wh;                       dst = WhT1; }
  else               { src = Wh + (size_t)1024 * 4096; dst = WhT2; }
#pragma unroll
  for (int ii = 0; ii < 16; ++ii) {
    int idx = ii * 256 + tid;
    int r = idx >> 6, c = idx & 63;
    int run = c >> 3, u = c & 7;
    int blkLoc = run >> 2, gate = run & 3;
    int g = gate * 1024 + (rt * 2 + blkLoc) * 8 + u;
    lds[r][blkLoc * 32 + u * 4 + gate] = src[(size_t)(kt * 64 + r) * 4096 + g];
  }
  __syncthreads();
#pragma unroll
  for (int ii = 0; ii < 16; ++ii) {
    int idx = ii * 256 + tid;
    int rw = idx >> 6, cw = idx & 63;
    dst[(size_t)(rt * 64 + rw) * 1024 + kt * 64 + cw] = f2bf(lds[cw][rw]);
  }
}

// -------- chunked GEMM group (persistent): 64 blocks, 32 chunks of 256 rows,
// 1 tile (128x128) per block per chunk.
// IS2=0: A = x (f32, rows remapped b*256+t), out -> xp1ring; gate: xp1 ring reuse.
// IS2=1: A = h1 read DIRECTLY from full-depth hpub1 ring (uncached); gate: scan1
//        chunk published + xp2 ring reuse vs scan2.
// C rows t-major (r = t*32+b), cols permuted; bias added here. C stores uncached.
// flags: [0..63] scan1, [64..127] scan2 (flag value = steps fully published+acked).
template <int IS2>
__device__ void gemm_grp(char* smem, int gb,
    const float* __restrict__ Af32, const u16* __restrict__ Ahp,
    const u16* __restrict__ Bt, const float* __restrict__ bias,
    u16* __restrict__ Cring, const int* flags, int* gdone) {
  u16* As = (u16*)smem;
  u16* Bs = (u16*)(smem + 16384);
  const int tid = threadIdx.x;
  const int lane = tid & 63, w = tid >> 6;
  const int wm = w >> 1, wn = w & 1;
  const int l15 = lane & 15, lq = lane >> 4;
  const int srow = tid >> 2, qd = tid & 3;
  const int mg = gb >> 5, ng = gb & 31;
  const u32 rsw = (u32)((l15 & 7) << 4);

  for (int c = 0; c < 32; ++c) {
    // ---- gate (once per chunk) ----
    if (w == 0) {
      const int thrA = IS2 ? 8 * (c + 1) : 8 * c - 24;  // scan1 flags
      const int thrB = 8 * c - 24;                       // scan2 flags (xp2 reuse)
      while (1) {
        bool ok = true;
        if (lane < 16) {
          u32x4 fv;
          const u32x4* fp = (const u32x4*)flags + lane;
          asm volatile("global_load_dwordx4 %0, %1, off sc0 sc1"
                       : "=v"(fv) : "v"(fp) : "memory");
          asm volatile("s_waitcnt vmcnt(0)" ::: "memory");
          __builtin_amdgcn_sched_barrier(0);
          ok = (int)fv[0] >= thrA && (int)fv[1] >= thrA &&
               (int)fv[2] >= thrA && (int)fv[3] >= thrA;
        } else if (IS2 && lane < 32) {
          u32x4 fv;
          const u32x4* fp = (const u32x4*)(flags + 64) + (lane - 16);
          asm volatile("global_load_dwordx4 %0, %1, off sc0 sc1"
                       : "=v"(fv) : "v"(fp) : "memory");
          asm volatile("s_waitcnt vmcnt(0)" ::: "memory");
          __builtin_amdgcn_sched_barrier(0);
          ok = (int)fv[0] >= thrB && (int)fv[1] >= thrB &&
               (int)fv[2] >= thrB && (int)fv[3] >= thrB;
        }
        if (__all(ok)) break;
        __builtin_amdgcn_s_sleep(8);
      }
    }
    __syncthreads();

    f32x4 acc[4][4];
#pragma unroll
    for (int i = 0; i < 4; ++i)
#pragma unroll
      for (int j = 0; j < 4; ++j) acc[i][j] = (f32x4){0.f, 0.f, 0.f, 0.f};

    for (int kt = 0; kt < 16; ++kt) {
      u32x4 aw[2][2], bv[2][2];
#pragma unroll
      for (int rr = 0; rr < 2; ++rr) {
        int row = rr * 64 + srow;
        const u32x4* bp = (const u32x4*)(Bt + (size_t)(ng * 128 + row) * 1024 + kt * 64 + qd * 16);
        bv[rr][0] = bp[0]; bv[rr][1] = bp[1];
        int rg = 256 * c + mg * 128 + row;
        if (IS2) {
          // h1 from hpub1 ring: slot t=rg>>5, batch b=rg&31, k-pack p=kt*8+qd*2
          int tq = rg >> 5, b2 = rg & 31;
          int p = kt * 8 + qd * 2;
          const char* ap = (const char*)Ahp + (size_t)tq * 65536 +
                           (size_t)(p * 32 + b2) * 16;
          asm volatile("global_load_dwordx4 %0, %1, off sc0 sc1"
                       : "=v"(aw[rr][0]) : "v"(ap) : "memory");
          asm volatile("global_load_dwordx4 %0, %1, off sc0 sc1"
                       : "=v"(aw[rr][1]) : "v"(ap + 512) : "memory");
        } else {
          const f32x4* ap = (const f32x4*)(Af32 +
              ((size_t)(rg & 31) * 256 + (rg >> 5)) * 1024 + kt * 64 + qd * 16);
          f32x4 a0 = ap[0], a1 = ap[1], a2 = ap[2], a3 = ap[3];
          aw[rr][0][0] = pk2(a0[0], a0[1]); aw[rr][0][1] = pk2(a0[2], a0[3]);
          aw[rr][0][2] = pk2(a1[0], a1[1]); aw[rr][0][3] = pk2(a1[2], a1[3]);
          aw[rr][1][0] = pk2(a2[0], a2[1]); aw[rr][1][1] = pk2(a2[2], a2[3]);
          aw[rr][1][2] = pk2(a3[0], a3[1]); aw[rr][1][3] = pk2(a3[2], a3[3]);
        }
      }
      __syncthreads();  // previous MFMA reads done before overwrite
      if (IS2) {
        asm volatile("s_waitcnt vmcnt(0)" ::: "memory");  // asm loads landed
        __builtin_amdgcn_sched_barrier(0);
      }
#pragma unroll
      for (int rr = 0; rr < 2; ++rr) {
        int row = rr * 64 + srow;
        u32 sw = (u32)((row & 7) << 4);
        int base = row * 128 + qd * 32;
        *(u32x4*)((char*)As + ((base) ^ sw)) = aw[rr][0];
        *(u32x4*)((char*)As + ((base + 16) ^ sw)) = aw[rr][1];
        *(u32x4*)((char*)Bs + ((base) ^ sw)) = bv[rr][0];
        *(u32x4*)((char*)Bs + ((base + 16) ^ sw)) = bv[rr][1];
      }
      __syncthreads();
#pragma unroll
      for (int k2 = 0; k2 < 2; ++k2) {
        short8 af[4], bf[4];
#pragma unroll
        for (int f = 0; f < 4; ++f) {
          af[f] = *(const short8*)((const char*)As +
                   (((wm * 64 + f * 16 + l15) * 128 + k2 * 64 + lq * 16) ^ rsw));
          bf[f] = *(const short8*)((const char*)Bs +
                   (((wn * 64 + f * 16 + l15) * 128 + k2 * 64 + lq * 16) ^ rsw));
        }
#pragma unroll
        for (int fi = 0; fi < 4; ++fi)
#pragma unroll
          for (int fj = 0; fj < 4; ++fj)
            acc[fi][fj] = MFMA16(af[fi], bf[fj], acc[fi][fj]);
      }
    }
    // ---- epilogue: +bias, store bf16 to ring slot c&3 (uncached) ----
#pragma unroll
    for (int fj = 0; fj < 4; ++fj) {
      int gc = ng * 128 + wn * 64 + fj * 16 + l15;
      float bvv = bias[permcol(gc)];
#pragma unroll
      for (int fi = 0; fi < 4; ++fi) {
        int rr0 = (c & 3) * 256 + mg * 128 + wm * 64 + fi * 16 + lq * 4;
#pragma unroll
        for (int r = 0; r < 4; ++r) {
          u32 vv = (u32)f2bf(acc[fi][fj][r] + bvv);
          const u16* cp = Cring + (size_t)(rr0 + r) * 4096 + gc;
          asm volatile("global_store_short %0, %1, off sc0 sc1"
                       :: "v"(cp), "v"(vv) : "memory");
        }
      }
    }
    asm volatile("s_waitcnt vmcnt(0)" ::: "memory");  // own stores acked
    __syncthreads();                                   // all waves drained
    if (tid == 0)
      __hip_atomic_fetch_add(gdone + c, 1, __ATOMIC_RELAXED, __HIP_MEMORY_SCOPE_AGENT);
  }
}

// -------- scan group (persistent): 64 blocks, 16 units each, K=1024 --------
// hpub = FULL-DEPTH poisoned ring (256 slots x 64KB, memset 0xFF per launch).
// Single-set data-poll (r9-proven register shape) with per-frag incremental
// re-poll. PRE-POLL DELAY: s_sleep(16) (~0.43us) before the first issue so
// round 1's L3 sample lands AFTER straggler peers' publishes are visible --
// turning the common detect from round 2 (T0+2RT) into round 1 (T0+delay+RT).
// PASSIVE FLAGS: wave0's poll vmcnt(0) at step t retires its own step-(t-1)
// publish stores, so B1(t) implies all publishes <= t-1 globally acked; tid0
// stores flag=t right after B1 at chunk boundaries (no chunk-end drain stall).
#define ISSUE_FRAG(B, i_) do { \
  const int g_ = (i_) >> 2, j_ = (i_) & 3; \
  if (j_ == 0) asm volatile("global_load_dwordx4 %0, %1, off sc0 sc1" \
                            : "=v"(B[i_]) : "v"(pa[g_]) : "memory"); \
  else if (j_ == 1) asm volatile("global_load_dwordx4 %0, %1, off offset:256 sc0 sc1" \
                                 : "=v"(B[i_]) : "v"(pa[g_]) : "memory"); \
  else if (j_ == 2) asm volatile("global_load_dwordx4 %0, %1, off offset:2048 sc0 sc1" \
                                 : "=v"(B[i_]) : "v"(pa[g_]) : "memory"); \
  else asm volatile("global_load_dwordx4 %0, %1, off offset:2304 sc0 sc1" \
                    : "=v"(B[i_]) : "v"(pa[g_]) : "memory"); \
} while (0)
#define DRAIN0() do { asm volatile("s_waitcnt vmcnt(0)" ::: "memory"); \
  __builtin_amdgcn_sched_barrier(0); } while (0)
// B[i] <-> ks = i>>1, bc = i&1
#define MFALL(B) do { _Pragma("unroll") for (int i_ = 0; i_ < 16; ++i_) { \
  const int ks_ = i_ >> 1, bc_ = i_ & 1; \
  acc[0][bc_] = MFMA16(afr[0][ks_], B[i_], acc[0][bc_]); \
  acc[1][bc_] = MFMA16(afr[1][ks_], B[i_], acc[1][bc_]); \
  acc[2][bc_] = MFMA16(afr[2][ks_], B[i_], acc[2][bc_]); \
  acc[3][bc_] = MFMA16(afr[3][ks_], B[i_], acc[3][bc_]); } } while (0)

template <int L>
__device__ void scan_grp(char* smem, int nb,
    const u16* __restrict__ xpring, const u16* __restrict__ Wt,
    const int* __restrict__ lengths, u64* hpub,
    int* flags_self, const int* gdone,
    float* __restrict__ outp, float* __restrict__ csf, float* __restrict__ hsf) {
  f32x4* partv = (f32x4*)smem;                   // 32KB
  u16* h_stage = (u16*)(smem + 32768);           // 1KB  [b][16u]
  float* out_stage = (float*)(smem + 33792);     // 2KB  [b][16u] (L=1)
  const int tid = threadIdx.x;
  const int lane = tid & 63, w = tid >> 6;
  const int l15 = lane & 15, q = lane >> 4;
  const int b = (w & 1) * 16 + l15;
  const int u0 = (w >> 1) * 4 + q;  // 0..7; second unit = u0+8
  const int len = lengths[b];

  // Wh A-fragments register-resident: 32 x short8 = 128 VGPR
  short8 afr[4][8];
#pragma unroll
  for (int tt = 0; tt < 4; ++tt)
#pragma unroll
    for (int ks = 0; ks < 8; ++ks)
      afr[tt][ks] = *(const short8*)(Wt + (size_t)(nb * 64 + tt * 16 + l15) * 1024 +
                                     w * 256 + ks * 32 + q * 8);

  f32x4 acc[4][2];
#pragma unroll
  for (int tt = 0; tt < 4; ++tt)
#pragma unroll
    for (int bc = 0; bc < 2; ++bc) acc[tt][bc] = (f32x4){0.f, 0.f, 0.f, 0.f};
  float c0 = 0.f, h0 = 0.f, c1 = 0.f, h1 = 0.f;

  // per-lane poll base (k-pack group stride 4096B; offsets 0/256/2048/2304)
  const int lane_base = (w * 32 + q) * 512 + l15 * 16;

  for (int t = 0; t < 256; ++t) {
    // ---- chunk boundary: xp-chunk gate (1 in 8 steps) ----
    if ((t & 7) == 0) {
      if (w == 0) {
        const int cidx = t >> 3;
        while (1) {
          bool ok = true;
          if (lane == 0) {
            u32 cd;
            asm volatile("global_load_dword %0, %1, off sc0 sc1"
                         : "=v"(cd) : "v"(gdone + cidx) : "memory");
            asm volatile("s_waitcnt vmcnt(0)" ::: "memory");
            __builtin_amdgcn_sched_barrier(0);
            ok = (int)cd >= 64;
          }
          if (__all(ok)) break;
          __builtin_amdgcn_s_sleep(2);
        }
      }
      __syncthreads();
    }

    // ---- xp loads (uncached; ring slot (t>>3)&3, row (t&7)*32+b), 2 units ----
    const u16* xa = xpring + ((size_t)((t >> 3) & 3) * 256 + (t & 7) * 32 + b) * 4096 +
                    nb * 64 + u0 * 4;
    u32x2 xpv0, xpv1;
    asm volatile("global_load_dwordx2 %0, %1, off sc0 sc1"
                 : "=v"(xpv0) : "v"(xa) : "memory");
    asm volatile("global_load_dwordx2 %0, %1, off sc0 sc1"
                 : "=v"(xpv1) : "v"(xa + 32) : "memory");

    // ---- h fragments: delayed first sample, single-set poll, per-frag re-poll ----
    if (t > 0) {
      const char* hp = (const char*)hpub + (size_t)(t - 1) * 65536 + lane_base;
      const char* pa[4];
#pragma unroll
      for (int g = 0; g < 4; ++g) pa[g] = hp + g * 4096;
      __builtin_amdgcn_s_sleep(16);  // ~0.43us: let peers' publishes reach L3
      short8 bfv[16];
#pragma unroll
      for (int i = 0; i < 16; ++i) ISSUE_FRAG(bfv, i);
      u32 done = 0;
      while (1) {
        DRAIN0();  // all issued loads landed (also retires own stores of t-1)
        {
#pragma unroll
          for (int i = 0; i < 16; ++i) {
            if (!(done & (1u << i))) {
              u32x4 vv = __builtin_bit_cast(u32x4, bfv[i]);
              bool ok = vv[0] != 0xFFFFFFFFu && vv[1] != 0xFFFFFFFFu &&
                        vv[2] != 0xFFFFFFFFu && vv[3] != 0xFFFFFFFFu;
              if (__all(ok)) done |= (1u << i);
            }
          }
        }
        if (done == 0xFFFFu) break;
#pragma unroll
        for (int i = 0; i < 16; ++i)
          if (!(done & (1u << i))) ISSUE_FRAG(bfv, i);
      }
      __builtin_amdgcn_sched_barrier(0);
      MFALL(bfv);
    } else {
      DRAIN0();
    }

    // ---- cross-wave K reduction (8 combos, 32 slots) ----
#pragma unroll
    for (int tt = 0; tt < 4; ++tt)
#pragma unroll
      for (int bc = 0; bc < 2; ++bc) {
        partv[(w * 8 + tt * 2 + bc) * 64 + lane] = acc[tt][bc];
        acc[tt][bc] = (f32x4){0.f, 0.f, 0.f, 0.f};
      }
    __syncthreads();  // B1: also implies all publishes <= t-1 globally acked
    if ((t & 7) == 0 && t > 0 && tid == 0)
      __hip_atomic_store(flags_self + nb, t, __ATOMIC_RELAXED,
                         __HIP_MEMORY_SCOPE_AGENT);
    f32x4 s0 = (f32x4){0.f, 0.f, 0.f, 0.f};
    f32x4 s1 = (f32x4){0.f, 0.f, 0.f, 0.f};
#pragma unroll
    for (int w2 = 0; w2 < 4; ++w2) {
      s0 += partv[(w2 * 8 + w) * 64 + lane];       // combo w   -> unit u0
      s1 += partv[(w2 * 8 + 4 + w) * 64 + lane];   // combo w+4 -> unit u0+8
    }

    bool mk = t < len;
    {
      float zi = s0[0] + bf2f((u16)(xpv0[0] & 0xffffu));
      float zj = s0[1] + bf2f((u16)(xpv0[0] >> 16));
      float zf = s0[2] + bf2f((u16)(xpv0[1] & 0xffffu)) + 1.f;  // FORGET_BIAS
      float zo = s0[3] + bf2f((u16)(xpv0[1] >> 16));
      float cn = sigm(zf) * c0 + sigm(zi) * tanh_(zj);
      float hn = sigm(zo) * tanh_(cn);
      c0 = mk ? cn : c0;
      h0 = mk ? hn : h0;
      float ov = mk ? hn : 0.f;
      h_stage[b * 16 + u0] = f2bf(ov);
      if (L) out_stage[b * 16 + u0] = ov;
    }
    {
      float zi = s1[0] + bf2f((u16)(xpv1[0] & 0xffffu));
      float zj = s1[1] + bf2f((u16)(xpv1[0] >> 16));
      float zf = s1[2] + bf2f((u16)(xpv1[1] & 0xffffu)) + 1.f;
      float zo = s1[3] + bf2f((u16)(xpv1[1] >> 16));
      float cn = sigm(zf) * c1 + sigm(zi) * tanh_(zj);
      float hn = sigm(zo) * tanh_(cn);
      c1 = mk ? cn : c1;
      h1 = mk ? hn : h1;
      float ov = mk ? hn : 0.f;
      h_stage[b * 16 + u0 + 8] = f2bf(ov);
      if (L) out_stage[b * 16 + u0 + 8] = ov;
    }
    __syncthreads();  // B2 (h_stage/out_stage complete)

    // ---- publish: fire-and-forget 16B stores (wave 0) ----
    if (tid < 64) {  // 2 k-packs x 32 batches x 16B
      int p = tid >> 5, bb = tid & 31;
      u32x4 pv = *(const u32x4*)((const char*)h_stage + bb * 32 + p * 16);
      char* hd = (char*)hpub + (size_t)t * 65536 +
                 (size_t)((nb * 2 + p) * 32 + bb) * 16;
      asm volatile("global_store_dwordx4 %0, %1, off sc0 sc1"
                   :: "v"(hd), "v"(pv) : "memory");
    }
    if (L && tid < 128) {  // rnnout rows (b, t), 16 cols
      int bb = tid >> 2, part = tid & 3;
      f32x4 ov = *(const f32x4*)(out_stage + bb * 16 + part * 4);
      *(f32x4*)(outp + ((size_t)bb * 256 + t) * 1024 + nb * 16 + part * 4) = ov;
    }
  }
  // final flag: all 256 steps published + acked
  DRAIN0();
  __syncthreads();
  if (tid == 0)
    __hip_atomic_store(flags_self + nb, 256, __ATOMIC_RELAXED,
                       __HIP_MEMORY_SCOPE_AGENT);
  csf[L * 32768 + b * 1024 + nb * 16 + u0] = c0;
  csf[L * 32768 + b * 1024 + nb * 16 + u0 + 8] = c1;
  hsf[L * 32768 + b * 1024 + nb * 16 + u0] = h0;
  hsf[L * 32768 + b * 1024 + nb * 16 + u0 + 8] = h1;
}

// -------- persistent pipeline: G1 64 | scan1 64 | G2 64 | scan2 64, 1 block/CU --------
__global__ __launch_bounds__(256, 1) void lstm_pipe(
    const float* __restrict__ x, const int* __restrict__ lengths,
    const float* __restrict__ bias,
    const u16* __restrict__ WxT1, const u16* __restrict__ WxT2,
    const u16* __restrict__ WhT1, const u16* __restrict__ WhT2,
    u16* xp1ring, u16* xp2ring,
    u64* hpub1, u64* hpub2, int* flags, float* outp) {
  __shared__ __align__(16) char smem[35840];
  int* g1done = flags + 128;   // 32 ints
  int* g2done = flags + 160;   // 32 ints
  const int bid = blockIdx.x;
  float* csf = outp + RN_;
  float* hsf = csf + 65536;
  if (bid < 64)
    gemm_grp<0>(smem, bid, x, nullptr, WxT1, bias, xp1ring, flags, g1done);
  else if (bid < 128)
    scan_grp<0>(smem, bid - 64, xp1ring, WhT1, lengths, hpub1, flags, g1done,
                outp, csf, hsf);
  else if (bid < 192)
    gemm_grp<1>(smem, bid - 128, nullptr, (const u16*)hpub1, WxT2, bias + 4096,
                xp2ring, flags, g2done);
  else
    scan_grp<1>(smem, bid - 192, xp2ring, WhT2, lengths, hpub2, flags + 64, g2done,
                outp, csf, hsf);
}

// -------- workspace layout (96MB + flags; proven budget) --------
#define WS_WXT1 0u
#define WS_WXT2 (8u << 20)
#define WS_WHT1 (16u << 20)
#define WS_WHT2 (24u << 20)
#define WS_XP1 (32u << 20)    // 4 slots x 256 rows x 4096 x 2B = 8MB
#define WS_XP2 (48u << 20)    // 8MB
#define WS_HPUB1 (64u << 20)  // 256 slots x 64KB = 16MB (full depth, poisoned)
#define WS_HPUB2 (80u << 20)  // 16MB (poisoned)
#define WS_FLAGS (96u << 20)  // 128 scan flags + 2x32 chunk counters

extern "C" void kernel_launch(void* const* d_in, const int* in_sizes, int n_in,
                              void* d_out, int out_size, void* d_ws, size_t ws_size,
                              hipStream_t stream) {
  const float* x = (const float*)d_in[0];
  const int* lengths = (const int*)d_in[1];
  const float* Wx = (const float*)d_in[2];
  const float* Wh = (const float*)d_in[3];
  const float* bias = (const float*)d_in[4];
  float* outp = (float*)d_out;

  if (ws_size < (size_t)WS_FLAGS + 4096) return;  // fail loudly (output stays poison)

  char* ws = (char*)d_ws;
  u16* WxT1 = (u16*)(ws + WS_WXT1);
  u16* WxT2 = (u16*)(ws + WS_WXT2);
  u16* WhT1 = (u16*)(ws + WS_WHT1);
  u16* WhT2 = (u16*)(ws + WS_WHT2);
  u16* xp1ring = (u16*)(ws + WS_XP1);
  u16* xp2ring = (u16*)(ws + WS_XP2);
  u64* hpub1 = (u64*)(ws + WS_HPUB1);
  u64* hpub2 = (u64*)(ws + WS_HPUB2);
  int* flags = (int*)(ws + WS_FLAGS);

  hipMemsetAsync(flags, 0, 2048, stream);
  hipMemsetAsync(hpub1, 0xFF, 32u << 20, stream);  // poison both hpub rings (NaN)
  transpose_convert<<<4096, 256, 0, stream>>>(Wx, Wh, WxT1, WxT2, WhT1, WhT2);
  lstm_pipe<<<256, 256, 0, stream>>>(x, lengths, bias, WxT1, WxT2, WhT1, WhT2,
                                     xp1ring, xp2ring, hpub1, hpub2, flags, outp);
}